// Round 11
// baseline (89.149 us; speedup 1.0000x reference)
//
#include <hip/hip_runtime.h>
#include <hip/hip_bf16.h>

typedef __attribute__((ext_vector_type(8))) short short8;
typedef __attribute__((ext_vector_type(4))) float floatx4;

#define B_SZ   64
#define N_TOK  32
#define S_TOK  1024
#define D_DIM  128
#define ALPHA  0.3f

#define STRIP_S     64
#define STRIP_BYTES (STRIP_S * D_DIM * 4)   // 32768 B of fp32
#define NSTRIP      (S_TOK / STRIP_S)       // 16
#define C_EL        (S_TOK * D_DIM)         // 131072 elements per doc batch
#define QN          ((size_t)B_SZ * N_TOK * D_DIM)   // 262144

__device__ __forceinline__ short f2bf(float f) {
    __hip_bfloat16 h = __float2bfloat16(f);
    return __builtin_bit_cast(short, h);
}

__device__ __forceinline__ short8 cvt8(const float* __restrict__ p) {
    floatx4 f0 = *reinterpret_cast<const floatx4*>(p);
    floatx4 f1 = *reinterpret_cast<const floatx4*>(p + 4);
    short8 r;
    r[0] = f2bf(f0[0]); r[1] = f2bf(f0[1]); r[2] = f2bf(f0[2]); r[3] = f2bf(f0[3]);
    r[4] = f2bf(f1[0]); r[5] = f2bf(f1[1]); r[6] = f2bf(f1[2]); r[7] = f2bf(f1[3]);
    return r;
}

// Q only: plain fp32 -> bf16. grid (QN/8/256 = 128, 2). D is no longer
// pre-converted: the scores kernel stages raw fp32 D via per-lane gather.
__global__ __launch_bounds__(256) void cvt_q_kernel(
    const float* __restrict__ q, const float* __restrict__ tq,
    __hip_bfloat16* __restrict__ qb, __hip_bfloat16* __restrict__ tqb) {
    const float* src = blockIdx.y ? tq : q;
    __hip_bfloat16* dst = blockIdx.y ? tqb : qb;
    int idx = blockIdx.x * 256 + threadIdx.x;
    *reinterpret_cast<short8*>(dst + (size_t)idx * 8) = cvt8(src + (size_t)idx * 8);
}

__device__ __forceinline__ void gload_lds16(const void* g, void* l) {
    __builtin_amdgcn_global_load_lds(
        (const __attribute__((address_space(1))) unsigned int*)g,
        (__attribute__((address_space(3))) unsigned int*)l, 16, 0, 0);
}

// Grid: (c = 64, bg = 4, which = 2) = 512 blocks (2/CU), 256 threads (4 waves).
// Wave w owns 4 batches b0 = bg*16 + w*4 .. +3 (M = 128 rows per wave).
// D[c] staged as RAW FP32 strips via global_load_lds with per-lane GATHERED
// source addresses implementing the fragment permutation (LDS stays linear).
// LDS granule g (16 B) within a strip:
//   g = sub*1024 + (ks*2+nt)*128 + eh*64 + li   (li = lg*16+lr)
//   holds fp32 D[s = sub*32 + nt*16 + lr][k = ks*32 + lg*8 + eh*4 .. +3].
// Compute converts fp32 -> bf16 in-register (r10 compute structure otherwise).
__global__ __launch_bounds__(256, 2) void maxsim_scores_kernel(
    const __hip_bfloat16* __restrict__ qb, const __hip_bfloat16* __restrict__ tqb,
    const float* __restrict__ d, const float* __restrict__ td,
    float* __restrict__ scores_ws /* [2][64][64] */) {

    const int c     = blockIdx.x;
    const int bg    = blockIdx.y;
    const int which = blockIdx.z;
    const __hip_bfloat16* Q = which ? tqb : qb;
    const float*          D = which ? td  : d;
    float* out = scores_ws + which * (B_SZ * B_SZ);

    const int tid = threadIdx.x;
    const int w   = tid >> 6;     // wave 0..3
    const int l   = tid & 63;     // lane
    const int lg  = l >> 4;       // k-subrange 0..3
    const int lr  = l & 15;       // row/col within 16

    const int b0 = bg * 16 + w * 4;

    __shared__ __align__(16) char smem[2 * STRIP_BYTES];  // 64 KB dbuf

    // A fragments: mt 0..7 -> batch b0 + (mt>>1), row (mt&1)*16 + lr. 128 regs.
    short8 afrag[8][4];
#pragma unroll
    for (int mt = 0; mt < 8; ++mt)
#pragma unroll
        for (int ks = 0; ks < 4; ++ks)
            afrag[mt][ks] = *reinterpret_cast<const short8*>(
                Q + ((size_t)(b0 + (mt >> 1)) * N_TOK + (mt & 1) * 16 + lr) * D_DIM
                  + ks * 32 + lg * 8);
#pragma unroll
    for (int mt = 0; mt < 8; ++mt)
#pragma unroll
        for (int ks = 0; ks < 4; ++ks)
            asm volatile("" : "+v"(afrag[mt][ks]));

    float runmax[8][4];
#pragma unroll
    for (int mt = 0; mt < 8; ++mt)
#pragma unroll
        for (int j = 0; j < 4; ++j) runmax[mt][j] = -INFINITY;

    const floatx4 fzero = {0.f, 0.f, 0.f, 0.f};

    // Loop-invariant per-thread gather offsets (bytes within a strip).
    unsigned goff[8];
#pragma unroll
    for (int i = 0; i < 8; ++i) {
        int g   = i * 256 + tid;
        int sub = g >> 10;
        int chq = (g >> 7) & 7;          // ks*2 + nt
        int eh  = (g >> 6) & 1;
        int li  = g & 63;
        int ks  = chq >> 1, nt = chq & 1;
        int lg2 = li >> 4,  lr2 = li & 15;
        int s_local = sub * 32 + nt * 16 + lr2;
        int k       = ks * 32 + lg2 * 8 + eh * 4;
        goff[i] = (unsigned)((s_local * D_DIM + k) * 4);
    }

    const char* gstrip = (const char*)(D + (size_t)c * C_EL);

    // Prologue: stage strip 0.
#pragma unroll
    for (int i = 0; i < 8; ++i)
        gload_lds16(gstrip + goff[i], smem + i * 4096 + tid * 16);
    __syncthreads();

    for (int st = 0; st < NSTRIP; ++st) {
        const char* bufc = smem + (size_t)(st & 1) * STRIP_BYTES;

        if (st + 1 < NSTRIP) {
            const char* gs = gstrip + (size_t)(st + 1) * STRIP_BYTES;
            char* bufn = smem + (size_t)((st + 1) & 1) * STRIP_BYTES;
#pragma unroll
            for (int i = 0; i < 8; ++i)
                gload_lds16(gs + goff[i], bufn + i * 4096 + tid * 16);
        }

        // 4 phases per strip: sub = ph>>1 (32-row half), nt = ph&1.
#pragma unroll
        for (int ph = 0; ph < 4; ++ph) {
            const char* base = bufc + (ph >> 1) * 16384 + (ph & 1) * 2048;

            short8 bf[4];
#pragma unroll
            for (int ks = 0; ks < 4; ++ks) {
                floatx4 lo = *reinterpret_cast<const floatx4*>(base + ks * 4096 + l * 16);
                floatx4 hi = *reinterpret_cast<const floatx4*>(base + ks * 4096 + 1024 + l * 16);
                short8 r;
                r[0] = f2bf(lo[0]); r[1] = f2bf(lo[1]); r[2] = f2bf(lo[2]); r[3] = f2bf(lo[3]);
                r[4] = f2bf(hi[0]); r[5] = f2bf(hi[1]); r[6] = f2bf(hi[2]); r[7] = f2bf(hi[3]);
                bf[ks] = r;
            }

            floatx4 acc[8];
#pragma unroll
            for (int mt = 0; mt < 8; ++mt)
                acc[mt] = __builtin_amdgcn_mfma_f32_16x16x32_bf16(
                    afrag[mt][0], bf[0], fzero, 0, 0, 0);
#pragma unroll
            for (int ks = 1; ks < 4; ++ks)
#pragma unroll
                for (int mt = 0; mt < 8; ++mt)
                    acc[mt] = __builtin_amdgcn_mfma_f32_16x16x32_bf16(
                        afrag[mt][ks], bf[ks], acc[mt], 0, 0, 0);

#pragma unroll
            for (int mt = 0; mt < 8; ++mt)
#pragma unroll
                for (int j = 0; j < 4; ++j)
                    runmax[mt][j] = fmaxf(runmax[mt][j], acc[mt][j]);
        }

        __syncthreads();  // dbuf protection (drains staging)
    }

    // Max over the 16 s-columns spread across lr.
#pragma unroll
    for (int mt = 0; mt < 8; ++mt)
#pragma unroll
        for (int j = 0; j < 4; ++j) {
            float v = runmax[mt][j];
            v = fmaxf(v, __shfl_xor(v, 1));
            v = fmaxf(v, __shfl_xor(v, 2));
            v = fmaxf(v, __shfl_xor(v, 4));
            v = fmaxf(v, __shfl_xor(v, 8));
            runmax[mt][j] = v;
        }

    // Per-batch row sums: batch b0+p covers mt = 2p, 2p+1 (rows lg*4+j).
#pragma unroll
    for (int p = 0; p < 4; ++p) {
        float s = 0.f;
#pragma unroll
        for (int j = 0; j < 4; ++j) s += runmax[2 * p][j] + runmax[2 * p + 1][j];
        s += __shfl_xor(s, 16);
        s += __shfl_xor(s, 32);
        if (l == 0) out[(b0 + p) * B_SZ + c] = s;
    }
}

// 1 block, 64 threads: final loss.
__global__ void loss_kernel(const float* __restrict__ scores_ws, float* __restrict__ out) {
    const float* sc = scores_ws;                 // student [64][64]
    const float* tc = scores_ws + B_SZ * B_SZ;   // teacher [64][64]
    const int b = threadIdx.x;                   // 0..63

    float pos = sc[b * B_SZ + b];
    float neg = -INFINITY;
    float msesum = 0.f;
#pragma unroll 8
    for (int cc = 0; cc < B_SZ; ++cc) {
        float s = sc[b * B_SZ + cc];
        float t = tc[b * B_SZ + cc];
        if (cc != b) neg = fmaxf(neg, s);
        _Float16 d16 = (_Float16)s - (_Float16)t;  // fp16 subtract (matches ref cast)
        _Float16 sq  = d16 * d16;                  // fp16 square
        msesum += (float)sq;                       // fp32 accumulation
    }
    float x = neg - pos;
    float sp = (x > 0.f) ? (x + log1pf(expf(-x))) : log1pf(expf(x));

#pragma unroll
    for (int m = 1; m < 64; m <<= 1) {
        sp     += __shfl_xor(sp, m);
        msesum += __shfl_xor(msesum, m);
    }
    if (b == 0) {
        float mse = msesum / 4096.f;
        mse = (float)(_Float16)mse;  // jnp.mean returns f16, then astype(f32)
        out[0] = sp / 64.f + ALPHA * mse;
    }
}

extern "C" void kernel_launch(void* const* d_in, const int* in_sizes, int n_in,
                              void* d_out, int out_size, void* d_ws, size_t ws_size,
                              hipStream_t stream) {
    const float* q  = (const float*)d_in[0];
    const float* d  = (const float*)d_in[1];
    const float* tq = (const float*)d_in[2];
    const float* td = (const float*)d_in[3];
    float* out = (float*)d_out;

    float* scores_ws = (float*)d_ws;                                  // 32 KB
    __hip_bfloat16* qb  = (__hip_bfloat16*)((char*)d_ws + 32768);
    __hip_bfloat16* tqb = qb + QN;

    cvt_q_kernel<<<dim3((unsigned)(QN / 8 / 256), 2), 256, 0, stream>>>(q, tq, qb, tqb);

    dim3 grid(B_SZ, B_SZ / 16, 2);
    maxsim_scores_kernel<<<grid, 256, 0, stream>>>(qb, tqb, d, td, scores_ws);
    loss_kernel<<<1, 64, 0, stream>>>(scores_ws, out);
}

// Round 12
// 80.611 us; speedup vs baseline: 1.1059x; 1.1059x over previous
//
#include <hip/hip_runtime.h>
#include <hip/hip_bf16.h>

typedef __attribute__((ext_vector_type(8))) short short8;
typedef __attribute__((ext_vector_type(4))) float floatx4;

#define B_SZ   64
#define N_TOK  32
#define S_TOK  1024
#define D_DIM  128
#define ALPHA  0.3f

#define STRIP_S     32
#define STRIP_BYTES (STRIP_S * D_DIM * 4)   // 16384 B of fp32
#define NSTRIP      (S_TOK / STRIP_S)       // 32
#define C_EL        (S_TOK * D_DIM)         // 131072 elements per doc batch

__device__ __forceinline__ short f2bf(float f) {
    __hip_bfloat16 h = __float2bfloat16(f);
    return __builtin_bit_cast(short, h);
}

__device__ __forceinline__ void gload_lds16(const void* g, void* l) {
    __builtin_amdgcn_global_load_lds(
        (const __attribute__((address_space(1))) unsigned int*)g,
        (__attribute__((address_space(3))) unsigned int*)l, 16, 0, 0);
}

// XOR involution within a strip: moves 16B granules WITHIN their 512B row
// (bits 4-6 ^= row&7). Row (bits 9+) unchanged -> global source stays
// row-contiguous (coalesced); LDS reads at stride 512B spread across 8
// 16B slots -> 2-way bank aliasing only (free).
__device__ __forceinline__ unsigned swz(unsigned y) {
    return y ^ (((y >> 9) & 7) << 4);
}

// Grid: (c = 64, bg = 4, which = 2) = 512 blocks (2/CU), 256 threads (4 waves).
// Wave w owns 4 batches b0 = bg*16 + w*4 .. +3 (M = 128 rows per wave).
// FULLY FUSED: no pre-conversion pass. Q fp32 -> bf16 in prologue registers.
// D staged as RAW FP32 strips: linear LDS dest, row-local-XOR'd global source,
// same XOR on the LDS read side (rule #21 both-sides). bf16 cvt in-register.
__global__ __launch_bounds__(256, 2) void maxsim_scores_kernel(
    const float* __restrict__ qf, const float* __restrict__ tqf,
    const float* __restrict__ d,  const float* __restrict__ td,
    float* __restrict__ scores_ws /* [2][64][64] */) {

    const int c     = blockIdx.x;
    const int bg    = blockIdx.y;
    const int which = blockIdx.z;
    const float* Q = which ? tqf : qf;
    const float* D = which ? td  : d;
    float* out = scores_ws + which * (B_SZ * B_SZ);

    const int tid = threadIdx.x;
    const int w   = tid >> 6;     // wave 0..3
    const int l   = tid & 63;     // lane
    const int lg  = l >> 4;       // k-subrange 0..3
    const int lr  = l & 15;       // row/col within 16

    const int b0 = bg * 16 + w * 4;

    __shared__ __align__(16) char smem[2 * STRIP_BYTES];  // 32 KB dbuf

    // A fragments from fp32 Q, converted once in registers. 128 VGPR.
    short8 afrag[8][4];
#pragma unroll
    for (int mt = 0; mt < 8; ++mt)
#pragma unroll
        for (int ks = 0; ks < 4; ++ks) {
            const float* qp = Q + ((size_t)(b0 + (mt >> 1)) * N_TOK + (mt & 1) * 16 + lr) * D_DIM
                                + ks * 32 + lg * 8;
            floatx4 f0 = *reinterpret_cast<const floatx4*>(qp);
            floatx4 f1 = *reinterpret_cast<const floatx4*>(qp + 4);
            short8 r;
            r[0] = f2bf(f0[0]); r[1] = f2bf(f0[1]); r[2] = f2bf(f0[2]); r[3] = f2bf(f0[3]);
            r[4] = f2bf(f1[0]); r[5] = f2bf(f1[1]); r[6] = f2bf(f1[2]); r[7] = f2bf(f1[3]);
            afrag[mt][ks] = r;
        }
    // Keep-alive: forbid sinking/remat of afrag into the strip loop.
#pragma unroll
    for (int mt = 0; mt < 8; ++mt)
#pragma unroll
        for (int ks = 0; ks < 4; ++ks)
            asm volatile("" : "+v"(afrag[mt][ks]));

    float runmax[8][4];
#pragma unroll
    for (int mt = 0; mt < 8; ++mt)
#pragma unroll
        for (int j = 0; j < 4; ++j) runmax[mt][j] = -INFINITY;

    const floatx4 fzero = {0.f, 0.f, 0.f, 0.f};

    const char* gstrip = (const char*)(D + (size_t)c * C_EL);

    // Per-thread staging offsets: LDS dest linear y_i, global src swz(y_i)
    // (swz is loop-invariant; strip base added per iteration).
    unsigned ydst[4], ysrc[4];
#pragma unroll
    for (int i = 0; i < 4; ++i) {
        ydst[i] = i * 4096 + tid * 16;
        ysrc[i] = swz(ydst[i]);
    }

    // Prologue: stage strip 0.
#pragma unroll
    for (int i = 0; i < 4; ++i)
        gload_lds16(gstrip + ysrc[i], smem + ydst[i]);
    __syncthreads();

    // Read-side swizzle constant: s_local = nt*16 + lr, s_local&7 == lr&7.
    const unsigned xr = ((unsigned)(lr & 7)) << 4;

    for (int st = 0; st < NSTRIP; ++st) {
        const char* bufc = smem + (size_t)(st & 1) * STRIP_BYTES;

        if (st + 1 < NSTRIP) {
            const char* gs = gstrip + (size_t)(st + 1) * STRIP_BYTES;
            char* bufn = smem + (size_t)((st + 1) & 1) * STRIP_BYTES;
#pragma unroll
            for (int i = 0; i < 4; ++i)
                gload_lds16(gs + ysrc[i], bufn + ydst[i]);
        }

        // 2 nt-phases per strip (rows nt*16 + lr).
#pragma unroll
        for (int nt = 0; nt < 2; ++nt) {
            const unsigned rowbyte = (unsigned)((nt * 16 + lr) * 512);

            short8 bf[4];
#pragma unroll
            for (int ks = 0; ks < 4; ++ks) {
                unsigned lo = (rowbyte + (unsigned)(ks * 128 + lg * 32)) ^ xr;
                floatx4 f0 = *reinterpret_cast<const floatx4*>(bufc + lo);
                floatx4 f1 = *reinterpret_cast<const floatx4*>(bufc + (lo ^ 16u));
                short8 r;
                r[0] = f2bf(f0[0]); r[1] = f2bf(f0[1]); r[2] = f2bf(f0[2]); r[3] = f2bf(f0[3]);
                r[4] = f2bf(f1[0]); r[5] = f2bf(f1[1]); r[6] = f2bf(f1[2]); r[7] = f2bf(f1[3]);
                bf[ks] = r;
            }

            floatx4 acc[8];
            // ks = 0 consumes loop-invariant fzero as C: no acc zeroing.
#pragma unroll
            for (int mt = 0; mt < 8; ++mt)
                acc[mt] = __builtin_amdgcn_mfma_f32_16x16x32_bf16(
                    afrag[mt][0], bf[0], fzero, 0, 0, 0);
#pragma unroll
            for (int ks = 1; ks < 4; ++ks)
#pragma unroll
                for (int mt = 0; mt < 8; ++mt)
                    acc[mt] = __builtin_amdgcn_mfma_f32_16x16x32_bf16(
                        afrag[mt][ks], bf[ks], acc[mt], 0, 0, 0);

#pragma unroll
            for (int mt = 0; mt < 8; ++mt)
#pragma unroll
                for (int j = 0; j < 4; ++j)
                    runmax[mt][j] = fmaxf(runmax[mt][j], acc[mt][j]);
        }

        __syncthreads();  // dbuf protection (drains staging)
    }

    // Max over the 16 s-columns spread across lr.
#pragma unroll
    for (int mt = 0; mt < 8; ++mt)
#pragma unroll
        for (int j = 0; j < 4; ++j) {
            float v = runmax[mt][j];
            v = fmaxf(v, __shfl_xor(v, 1));
            v = fmaxf(v, __shfl_xor(v, 2));
            v = fmaxf(v, __shfl_xor(v, 4));
            v = fmaxf(v, __shfl_xor(v, 8));
            runmax[mt][j] = v;
        }

    // Per-batch row sums: batch b0+p covers mt = 2p, 2p+1 (rows lg*4+j).
#pragma unroll
    for (int p = 0; p < 4; ++p) {
        float s = 0.f;
#pragma unroll
        for (int j = 0; j < 4; ++j) s += runmax[2 * p][j] + runmax[2 * p + 1][j];
        s += __shfl_xor(s, 16);
        s += __shfl_xor(s, 32);
        if (l == 0) out[(b0 + p) * B_SZ + c] = s;
    }
}

// 1 block, 64 threads: final loss.
__global__ void loss_kernel(const float* __restrict__ scores_ws, float* __restrict__ out) {
    const float* sc = scores_ws;                 // student [64][64]
    const float* tc = scores_ws + B_SZ * B_SZ;   // teacher [64][64]
    const int b = threadIdx.x;                   // 0..63

    float pos = sc[b * B_SZ + b];
    float neg = -INFINITY;
    float msesum = 0.f;
#pragma unroll 8
    for (int cc = 0; cc < B_SZ; ++cc) {
        float s = sc[b * B_SZ + cc];
        float t = tc[b * B_SZ + cc];
        if (cc != b) neg = fmaxf(neg, s);
        _Float16 d16 = (_Float16)s - (_Float16)t;  // fp16 subtract (matches ref cast)
        _Float16 sq  = d16 * d16;                  // fp16 square
        msesum += (float)sq;                       // fp32 accumulation
    }
    float x = neg - pos;
    float sp = (x > 0.f) ? (x + log1pf(expf(-x))) : log1pf(expf(x));

#pragma unroll
    for (int m = 1; m < 64; m <<= 1) {
        sp     += __shfl_xor(sp, m);
        msesum += __shfl_xor(msesum, m);
    }
    if (b == 0) {
        float mse = msesum / 4096.f;
        mse = (float)(_Float16)mse;  // jnp.mean returns f16, then astype(f32)
        out[0] = sp / 64.f + ALPHA * mse;
    }
}

extern "C" void kernel_launch(void* const* d_in, const int* in_sizes, int n_in,
                              void* d_out, int out_size, void* d_ws, size_t ws_size,
                              hipStream_t stream) {
    const float* q  = (const float*)d_in[0];
    const float* d  = (const float*)d_in[1];
    const float* tq = (const float*)d_in[2];
    const float* td = (const float*)d_in[3];
    float* out = (float*)d_out;

    float* scores_ws = (float*)d_ws;   // 2*64*64 floats = 32 KB

    dim3 grid(B_SZ, B_SZ / 16, 2);
    maxsim_scores_kernel<<<grid, 256, 0, stream>>>(q, tq, d, td, scores_ws);
    loss_kernel<<<1, 64, 0, stream>>>(scores_ws, out);
}

// Round 13
// 76.184 us; speedup vs baseline: 1.1702x; 1.0581x over previous
//
#include <hip/hip_runtime.h>
#include <hip/hip_bf16.h>

typedef __attribute__((ext_vector_type(8))) short short8;
typedef __attribute__((ext_vector_type(4))) float floatx4;

#define B_SZ   64
#define N_TOK  32
#define S_TOK  1024
#define D_DIM  128
#define ALPHA  0.3f

#define STRIP_S     32
#define STRIP_EL    (STRIP_S * D_DIM)       // 4096 elements
#define STRIP_BYTES (STRIP_EL * 2)          // 8192 B
#define NSTRIP      (S_TOK / STRIP_S)       // 32
#define NBUF        4                       // ring, 3 strips in flight
#define C_EL        (S_TOK * D_DIM)         // 131072 elements per doc batch

#define DBLK (B_SZ * S_TOK * D_DIM / 8 / 256)   // 4096 blocks for D part
#define QBLK (B_SZ * N_TOK * D_DIM / 8 / 256)   // 128 blocks for Q part

#define WAITV_(N) asm volatile("s_waitcnt vmcnt(" #N ")" ::: "memory")
#define WAITV(N)  WAITV_(N)

__device__ __forceinline__ short f2bf(float f) {
    __hip_bfloat16 h = __float2bfloat16(f);
    return __builtin_bit_cast(short, h);
}

__device__ __forceinline__ short8 cvt8(const float* __restrict__ p) {
    floatx4 f0 = *reinterpret_cast<const floatx4*>(p);
    floatx4 f1 = *reinterpret_cast<const floatx4*>(p + 4);
    short8 r;
    r[0] = f2bf(f0[0]); r[1] = f2bf(f0[1]); r[2] = f2bf(f0[2]); r[3] = f2bf(f0[3]);
    r[4] = f2bf(f1[0]); r[5] = f2bf(f1[1]); r[6] = f2bf(f1[2]); r[7] = f2bf(f1[3]);
    return r;
}

// One launch converts everything. grid (DBLK + QBLK, 2).
// D part (layout verified r3-r10): fp32 -> bf16 with fragment permutation:
//   dst pos = c*C_EL + st*STRIP_EL + (ks*2+nt)*512 + (lg*16+lr)*8
//   where s = st*32 + nt*16 + lr, k = ks*32 + lg*8.
// Q part: plain layout-preserving fp32 -> bf16.
__global__ __launch_bounds__(256) void cvt_all_kernel(
    const float* __restrict__ q,  const float* __restrict__ d,
    const float* __restrict__ tq, const float* __restrict__ td,
    __hip_bfloat16* __restrict__ qb,  __hip_bfloat16* __restrict__ db,
    __hip_bfloat16* __restrict__ tqb, __hip_bfloat16* __restrict__ tdb) {
    const int which = blockIdx.y;
    if (blockIdx.x >= DBLK) {
        const float* src = which ? tq : q;
        __hip_bfloat16* dst = which ? tqb : qb;
        int idx = (blockIdx.x - DBLK) * 256 + threadIdx.x;
        *reinterpret_cast<short8*>(dst + (size_t)idx * 8) = cvt8(src + (size_t)idx * 8);
    } else {
        const float* src = which ? td : d;
        __hip_bfloat16* dst = which ? tdb : db;
        int idx = blockIdx.x * 256 + threadIdx.x;
        int kc = idx & 15;            // k-chunk 0..15
        int s  = (idx >> 4) & (S_TOK - 1);
        int c  = idx >> 14;
        int st = s >> 5, nt = (s >> 4) & 1, lr = s & 15;
        int ks = kc >> 2, lg = kc & 3;
        size_t dpos = (size_t)c * C_EL + (size_t)st * STRIP_EL
                    + (size_t)(ks * 2 + nt) * 512 + (size_t)(lg * 16 + lr) * 8;
        *reinterpret_cast<short8*>(dst + dpos) = cvt8(src + (size_t)idx * 8);
    }
}

__device__ __forceinline__ void gload_lds16(const void* g, void* l) {
    __builtin_amdgcn_global_load_lds(
        (const __attribute__((address_space(1))) unsigned int*)g,
        (__attribute__((address_space(3))) unsigned int*)l, 16, 0, 0);
}

// Grid: (c = 64, bg = 4, which = 2) = 512 blocks (2/CU), 256 threads (4 waves).
// Wave w owns 4 batches b0 = bg*16 + w*4 .. +3 (M = 128 rows per wave).
// m201-style per-phase schedule: per strip, 2 phases of
//   {pre-issue ds_read; (ph0: gload st+3); barrier; lgkmcnt(0)+schedbar;
//    setprio(1) MFMA setprio(0); fmax; closing barrier}
// Counted vmcnt publishes strip st+1 at strip st's closing barrier.
__global__ __launch_bounds__(256, 2) void maxsim_scores_kernel(
    const __hip_bfloat16* __restrict__ qb,  const __hip_bfloat16* __restrict__ db,
    const __hip_bfloat16* __restrict__ tqb, const __hip_bfloat16* __restrict__ tdb,
    float* __restrict__ scores_ws /* [2][64][64] */) {

    const int c     = blockIdx.x;
    const int bg    = blockIdx.y;
    const int which = blockIdx.z;
    const __hip_bfloat16* Q = which ? tqb : qb;
    const __hip_bfloat16* D = which ? tdb : db;
    float* out = scores_ws + which * (B_SZ * B_SZ);

    const int tid = threadIdx.x;
    const int w   = tid >> 6;     // wave 0..3
    const int l   = tid & 63;     // lane
    const int lg  = l >> 4;       // k-subrange 0..3
    const int lr  = l & 15;       // row/col within 16

    const int b0 = bg * 16 + w * 4;

    __shared__ __align__(16) char smem[NBUF * STRIP_BYTES];  // 32 KB ring

    // A fragments: mt 0..7 -> batch b0 + (mt>>1), row (mt&1)*16 + lr. 128 regs.
    short8 afrag[8][4];
#pragma unroll
    for (int mt = 0; mt < 8; ++mt)
#pragma unroll
        for (int ks = 0; ks < 4; ++ks)
            afrag[mt][ks] = *reinterpret_cast<const short8*>(
                Q + ((size_t)(b0 + (mt >> 1)) * N_TOK + (mt & 1) * 16 + lr) * D_DIM
                  + ks * 32 + lg * 8);
#pragma unroll
    for (int mt = 0; mt < 8; ++mt)
#pragma unroll
        for (int ks = 0; ks < 4; ++ks)
            asm volatile("" : "+v"(afrag[mt][ks]));

    float runmax[8][4];
#pragma unroll
    for (int mt = 0; mt < 8; ++mt)
#pragma unroll
        for (int j = 0; j < 4; ++j) runmax[mt][j] = -INFINITY;

    const floatx4 fzero = {0.f, 0.f, 0.f, 0.f};

    const char* gstrip = (const char*)(D + (size_t)c * C_EL);
    const unsigned y0 = tid * 16;
    const unsigned y1 = 4096 + tid * 16;

    // Prologue: stage strips 0..2 into ring slots 0..2; publish strip 0.
#pragma unroll
    for (int p = 0; p < 3; ++p) {
        gload_lds16(gstrip + (size_t)p * STRIP_BYTES + y0, smem + p * STRIP_BYTES + y0);
        gload_lds16(gstrip + (size_t)p * STRIP_BYTES + y1, smem + p * STRIP_BYTES + y1);
    }
    WAITV(4);                          // strip 0 (this wave's part) landed
    __builtin_amdgcn_s_barrier();      // all waves: strip 0 published

    for (int st = 0; st < NSTRIP; ++st) {
        const char* bufc = smem + (size_t)(st & (NBUF - 1)) * STRIP_BYTES;

        // ---------------- phase 0 (nt = 0) ----------------
        short8 bf0[4];
#pragma unroll
        for (int ks = 0; ks < 4; ++ks)
            bf0[ks] = *reinterpret_cast<const short8*>(bufc + (ks * 2) * 1024 + l * 16);

        if (st < NSTRIP - 3) {         // issue strip st+3 into slot (st+3)&3
            const char* gs = gstrip + (size_t)(st + 3) * STRIP_BYTES;
            char* bufn = smem + (size_t)((st + 3) & (NBUF - 1)) * STRIP_BYTES;
            gload_lds16(gs + y0, bufn + y0);
            gload_lds16(gs + y1, bufn + y1);
        }

        __builtin_amdgcn_s_barrier();
        asm volatile("s_waitcnt lgkmcnt(0)" ::: "memory");
        __builtin_amdgcn_sched_barrier(0);
        __builtin_amdgcn_s_setprio(1);
        floatx4 acc[8];
#pragma unroll
        for (int mt = 0; mt < 8; ++mt)
            acc[mt] = __builtin_amdgcn_mfma_f32_16x16x32_bf16(
                afrag[mt][0], bf0[0], fzero, 0, 0, 0);
#pragma unroll
        for (int ks = 1; ks < 4; ++ks)
#pragma unroll
            for (int mt = 0; mt < 8; ++mt)
                acc[mt] = __builtin_amdgcn_mfma_f32_16x16x32_bf16(
                    afrag[mt][ks], bf0[ks], acc[mt], 0, 0, 0);
        __builtin_amdgcn_s_setprio(0);
#pragma unroll
        for (int mt = 0; mt < 8; ++mt)
#pragma unroll
            for (int j = 0; j < 4; ++j)
                runmax[mt][j] = fmaxf(runmax[mt][j], acc[mt][j]);
        __builtin_amdgcn_s_barrier();

        // ---------------- phase 1 (nt = 1) ----------------
        short8 bf1[4];
#pragma unroll
        for (int ks = 0; ks < 4; ++ks)
            bf1[ks] = *reinterpret_cast<const short8*>(bufc + (ks * 2 + 1) * 1024 + l * 16);

        __builtin_amdgcn_s_barrier();
        asm volatile("s_waitcnt lgkmcnt(0)" ::: "memory");
        __builtin_amdgcn_sched_barrier(0);
        __builtin_amdgcn_s_setprio(1);
        floatx4 acc1[8];
#pragma unroll
        for (int mt = 0; mt < 8; ++mt)
            acc1[mt] = __builtin_amdgcn_mfma_f32_16x16x32_bf16(
                afrag[mt][0], bf1[0], fzero, 0, 0, 0);
#pragma unroll
        for (int ks = 1; ks < 4; ++ks)
#pragma unroll
            for (int mt = 0; mt < 8; ++mt)
                acc1[mt] = __builtin_amdgcn_mfma_f32_16x16x32_bf16(
                    afrag[mt][ks], bf1[ks], acc1[mt], 0, 0, 0);
        __builtin_amdgcn_s_setprio(0);
#pragma unroll
        for (int mt = 0; mt < 8; ++mt)
#pragma unroll
            for (int j = 0; j < 4; ++j)
                runmax[mt][j] = fmaxf(runmax[mt][j], acc1[mt][j]);

        // Publish strip st+1 at the closing barrier. Outstanding per wave:
        // st+1, st+2, st+3 (2 each) in steady state -> wait to 4.
        if (st < NSTRIP - 3)       WAITV(4);
        else if (st == NSTRIP - 3) WAITV(2);
        else if (st == NSTRIP - 2) WAITV(0);
        __builtin_amdgcn_s_barrier();
    }

    // Max over the 16 s-columns spread across lr.
#pragma unroll
    for (int mt = 0; mt < 8; ++mt)
#pragma unroll
        for (int j = 0; j < 4; ++j) {
            float v = runmax[mt][j];
            v = fmaxf(v, __shfl_xor(v, 1));
            v = fmaxf(v, __shfl_xor(v, 2));
            v = fmaxf(v, __shfl_xor(v, 4));
            v = fmaxf(v, __shfl_xor(v, 8));
            runmax[mt][j] = v;
        }

    // Per-batch row sums: batch b0+p covers mt = 2p, 2p+1 (rows lg*4+j).
#pragma unroll
    for (int p = 0; p < 4; ++p) {
        float s = 0.f;
#pragma unroll
        for (int j = 0; j < 4; ++j) s += runmax[2 * p][j] + runmax[2 * p + 1][j];
        s += __shfl_xor(s, 16);
        s += __shfl_xor(s, 32);
        if (l == 0) out[(b0 + p) * B_SZ + c] = s;
    }
}

// 1 block, 64 threads: final loss.
__global__ void loss_kernel(const float* __restrict__ scores_ws, float* __restrict__ out) {
    const float* sc = scores_ws;                 // student [64][64]
    const float* tc = scores_ws + B_SZ * B_SZ;   // teacher [64][64]
    const int b = threadIdx.x;                   // 0..63

    float pos = sc[b * B_SZ + b];
    float neg = -INFINITY;
    float msesum = 0.f;
#pragma unroll 8
    for (int cc = 0; cc < B_SZ; ++cc) {
        float s = sc[b * B_SZ + cc];
        float t = tc[b * B_SZ + cc];
        if (cc != b) neg = fmaxf(neg, s);
        _Float16 d16 = (_Float16)s - (_Float16)t;  // fp16 subtract (matches ref cast)
        _Float16 sq  = d16 * d16;                  // fp16 square
        msesum += (float)sq;                       // fp32 accumulation
    }
    float x = neg - pos;
    float sp = (x > 0.f) ? (x + log1pf(expf(-x))) : log1pf(expf(x));

#pragma unroll
    for (int m = 1; m < 64; m <<= 1) {
        sp     += __shfl_xor(sp, m);
        msesum += __shfl_xor(msesum, m);
    }
    if (b == 0) {
        float mse = msesum / 4096.f;
        mse = (float)(_Float16)mse;  // jnp.mean returns f16, then astype(f32)
        out[0] = sp / 64.f + ALPHA * mse;
    }
}

extern "C" void kernel_launch(void* const* d_in, const int* in_sizes, int n_in,
                              void* d_out, int out_size, void* d_ws, size_t ws_size,
                              hipStream_t stream) {
    const float* q  = (const float*)d_in[0];
    const float* d  = (const float*)d_in[1];
    const float* tq = (const float*)d_in[2];
    const float* td = (const float*)d_in[3];
    float* out = (float*)d_out;

    const size_t QN = (size_t)B_SZ * N_TOK * D_DIM;   // 262144
    const size_t DN = (size_t)B_SZ * S_TOK * D_DIM;   // 8388608

    float* scores_ws = (float*)d_ws;                                  // 32 KB
    __hip_bfloat16* qb  = (__hip_bfloat16*)((char*)d_ws + 32768);
    __hip_bfloat16* tqb = qb + QN;
    __hip_bfloat16* db  = tqb + QN;
    __hip_bfloat16* tdb = db + DN;

    cvt_all_kernel<<<dim3(DBLK + QBLK, 2), 256, 0, stream>>>(
        q, d, tq, td, qb, db, tqb, tdb);

    dim3 grid(B_SZ, B_SZ / 16, 2);
    maxsim_scores_kernel<<<grid, 256, 0, stream>>>(qb, db, tqb, tdb, scores_ws);
    loss_kernel<<<1, 64, 0, stream>>>(scores_ws, out);
}